// Round 1
// baseline (401.819 us; speedup 1.0000x reference)
//
#include <hip/hip_runtime.h>
#include <math.h>

// Problem constants (from setup_inputs): x [S,C,H,W] fp32, k = stride = 2
#define S   258
#define C   64
#define H   64
#define W   64
#define HO  32
#define WO  32
#define NP  (C * HO * WO)     // 65536 output windows per layer
#define L   (C * H * W)       // 262144 floats per layer
#define NCHUNK 8              // s-dimension split for occupancy in pass 1

// ---------------------------------------------------------------------------
// Pass 1: partial sum of |x[s]| over a chunk of symbol layers, per window elem.
// part layout: [chunk][elem(4)][NP]  (coalesced writes, coalesced reads in P2)
// ---------------------------------------------------------------------------
__global__ __launch_bounds__(256) void k_partial(const float* __restrict__ x,
                                                 float* __restrict__ part) {
    const int p     = blockIdx.x * 256 + threadIdx.x;   // window id
    const int chunk = blockIdx.y;
    const int c  = p >> 10;          // p / (HO*WO)
    const int hw = p & 1023;
    const int ho = hw >> 5;
    const int wo = hw & 31;
    const int base = c * (H * W) + (ho * 2) * W + wo * 2;

    // layers 1..S-1 split into NCHUNK contiguous ranges
    const int s0 = 1 + (257 * chunk) / NCHUNK;
    const int s1 = 1 + (257 * (chunk + 1)) / NCHUNK;

    float a0 = 0.f, a1 = 0.f, a2 = 0.f, a3 = 0.f;
    const float* px = x + (size_t)s0 * L + base;
    for (int s = s0; s < s1; ++s) {
        float2 r0 = *(const float2*)(px);
        float2 r1 = *(const float2*)(px + W);
        a0 += fabsf(r0.x); a1 += fabsf(r0.y);
        a2 += fabsf(r1.x); a3 += fabsf(r1.y);
        px += L;
    }
    float* q = part + (size_t)chunk * (4 * NP) + p;
    q[0]        = a0;
    q[NP]       = a1;
    q[2 * NP]   = a2;
    q[3 * NP]   = a3;
}

// ---------------------------------------------------------------------------
// Pass 2: per-window decision. Produces compact meta for pass 3 and writes
// x_min / x_max / x_true_out directly (they follow x_out in d_out).
//   x_min = l_star in BOTH branches (exact: center-out_abs = x0[p*]-eps[p*];
//           box: box_center - box_noise). x_max = exact ? hi[i*] : u_max.
// ---------------------------------------------------------------------------
__global__ __launch_bounds__(256) void k_meta(const float* __restrict__ x,
                                              const float* __restrict__ x_true,
                                              const float* __restrict__ part,
                                              float* __restrict__ mcenter,
                                              float* __restrict__ mnoise,
                                              int*   __restrict__ mpos,
                                              float* __restrict__ out_tail) {
    const int p = blockIdx.x * 256 + threadIdx.x;

    float e0 = 0.f, e1 = 0.f, e2 = 0.f, e3 = 0.f;
    #pragma unroll
    for (int j = 0; j < NCHUNK; ++j) {
        const float* q = part + (size_t)j * (4 * NP) + p;
        e0 += q[0];
        e1 += q[NP];
        e2 += q[2 * NP];
        e3 += q[3 * NP];
    }

    const int c  = p >> 10;
    const int hw = p & 1023;
    const int ho = hw >> 5;
    const int wo = hw & 31;
    const int base = c * (H * W) + (ho * 2) * W + wo * 2;

    float2 r0 = *(const float2*)(x + base);
    float2 r1 = *(const float2*)(x + base + W);
    // window element order matches pool_windows: e = kh*2 + kw
    float x0[4]  = { r0.x, r0.y, r1.x, r1.y };
    float eps[4] = { e0, e1, e2, e3 };
    float lo[4], hi[4];
    #pragma unroll
    for (int e = 0; e < 4; ++e) { lo[e] = x0[e] - eps[e]; hi[e] = x0[e] + eps[e]; }

    int istar = 0;  // argmax of lo, first-max tie-break like jnp.argmax
    #pragma unroll
    for (int e = 1; e < 4; ++e) if (lo[e] > lo[istar]) istar = e;

    const float lstar = lo[istar];
    const float umax  = fmaxf(fmaxf(hi[0], hi[1]), fmaxf(hi[2], hi[3]));
    float uoth = -INFINITY;
    #pragma unroll
    for (int e = 0; e < 4; ++e) if (e != istar) uoth = fmaxf(uoth, hi[e]);

    const bool exact = (lstar >= uoth);
    const int  off   = (istar & 1) + (istar >> 1) * W;
    const int  pos   = base + off;

    float center, noise, xmax;
    if (exact) {
        center = x0[istar];
        noise  = fabsf(x[(size_t)(S - 1) * L + pos]);
        xmax   = hi[istar];
    } else {
        center = 0.5f * (lstar + umax);
        noise  = 0.5f * (umax - lstar);
        xmax   = umax;
    }

    mcenter[p] = center;
    mnoise[p]  = noise;
    mpos[p]    = exact ? pos : -1;

    out_tail[p]      = lstar;   // x_min
    out_tail[NP + p] = xmax;    // x_max

    // x_true maxpool (same window geometry)
    float2 t0 = *(const float2*)(x_true + base);
    float2 t1 = *(const float2*)(x_true + base + W);
    out_tail[2 * NP + p] = fmaxf(fmaxf(t0.x, t0.y), fmaxf(t1.x, t1.y));
}

// ---------------------------------------------------------------------------
// Pass 3: write x_out [S, C, HO, WO]. eps layers are 0 unless exact (rare),
// in which case gather the affine form at the winning window position.
// ---------------------------------------------------------------------------
__global__ __launch_bounds__(256) void k_write(const float* __restrict__ x,
                                               const float* __restrict__ mcenter,
                                               const float* __restrict__ mnoise,
                                               const int*   __restrict__ mpos,
                                               float* __restrict__ out) {
    const int idx = blockIdx.x * 256 + threadIdx.x;
    const int s = idx >> 16;       // / NP (65536)
    const int p = idx & 65535;
    float v;
    if (s == 0) {
        v = mcenter[p];
    } else if (s == S - 1) {
        v = mnoise[p];
    } else {
        const int pos = mpos[p];
        v = 0.0f;
        if (pos >= 0) v = x[(size_t)s * L + pos];
    }
    out[idx] = v;
}

extern "C" void kernel_launch(void* const* d_in, const int* in_sizes, int n_in,
                              void* d_out, int out_size, void* d_ws, size_t ws_size,
                              hipStream_t stream) {
    const float* x      = (const float*)d_in[0];
    const float* x_true = (const float*)d_in[1];
    float* out = (float*)d_out;

    // workspace layout
    float* part    = (float*)d_ws;                        // NCHUNK*4*NP floats (8 MB)
    float* mcenter = part + (size_t)NCHUNK * 4 * NP;
    float* mnoise  = mcenter + NP;
    int*   mpos    = (int*)(mnoise + NP);

    const int XOUT = S * NP;   // x_out element count; tail = x_min,x_max,x_true_out

    k_partial<<<dim3(NP / 256, NCHUNK), 256, 0, stream>>>(x, part);
    k_meta<<<NP / 256, 256, 0, stream>>>(x, x_true, part, mcenter, mnoise, mpos,
                                         out + XOUT);
    k_write<<<XOUT / 256, 256, 0, stream>>>(x, mcenter, mnoise, mpos, out);
}

// Round 2
// 393.741 us; speedup vs baseline: 1.0205x; 1.0205x over previous
//
#include <hip/hip_runtime.h>
#include <math.h>

// Problem constants (from setup_inputs): x [S,C,H,W] fp32, k = stride = 2
#define S    258
#define C    64
#define H    64
#define W    64
#define HO   32
#define WO   32
#define NP   (C * HO * WO)      // 65536 windows per layer
#define L    (C * H * W)        // 262144 floats per layer
#define XOUT (S * NP)           // x_out element count

// ---------------------------------------------------------------------------
// Fused kernel: one block per (c, ho) row-pair = 32 windows.
//   Phase 1: 256 threads = 16 layer-groups x 16 float4-columns stream the
//            257 symbol layers (|.| sums), float4 loads (16 B/lane).
//   Phase 2: LDS tree-reduce across the 16 layer-groups.
//   Phase 3: 32 threads (one per window) make the zonotope decision and
//            write center / noise / x_min / x_max / x_true_out, and append
//            `exact` windows to a compact list for the gather kernel.
// Eps layers of x_out are all-zero except for exact windows -> handled by
// hipMemsetAsync + k_gather, never by bulk kernel stores.
// ---------------------------------------------------------------------------
__global__ __launch_bounds__(256) void k_main(const float* __restrict__ x,
                                              const float* __restrict__ x_true,
                                              float* __restrict__ out,
                                              int* __restrict__ counter,
                                              int2* __restrict__ exlist) {
    __shared__ float red[16][8][16];   // [layer-group][elem][col-pair]
    __shared__ float eps2[8][16];

    const int b   = blockIdx.x;
    const int c   = b >> 5;
    const int ho  = b & 31;
    const int tid = threadIdx.x;
    const int sg  = tid >> 4;          // layer group 0..15
    const int wp  = tid & 15;          // float4 column (covers windows 2wp,2wp+1)

    const int rowbase = c * (H * W) + ho * 2 * W;   // start of top row
    const int A = rowbase + wp * 4;

    // layers 1..257 split into 16 contiguous ranges
    const int s0 = 1 + ((257 * sg) >> 4);
    const int s1 = 1 + ((257 * (sg + 1)) >> 4);

    float a0=0.f,a1=0.f,a2=0.f,a3=0.f,a4=0.f,a5=0.f,a6=0.f,a7=0.f;
    const float* px = x + (size_t)s0 * L + A;
    for (int s = s0; s < s1; ++s) {
        float4 t = *(const float4*)(px);        // top row: wins 2wp|2wp+1
        float4 u = *(const float4*)(px + W);    // bottom row
        a0 += fabsf(t.x); a1 += fabsf(t.y); a2 += fabsf(t.z); a3 += fabsf(t.w);
        a4 += fabsf(u.x); a5 += fabsf(u.y); a6 += fabsf(u.z); a7 += fabsf(u.w);
        px += L;
    }
    red[sg][0][wp]=a0; red[sg][1][wp]=a1; red[sg][2][wp]=a2; red[sg][3][wp]=a3;
    red[sg][4][wp]=a4; red[sg][5][wp]=a5; red[sg][6][wp]=a6; red[sg][7][wp]=a7;
    __syncthreads();

    if (tid < 128) {
        const int e = tid >> 4, w = tid & 15;
        float sum = 0.f;
        #pragma unroll
        for (int j = 0; j < 16; ++j) sum += red[j][e][w];
        eps2[e][w] = sum;
    }
    __syncthreads();

    if (tid < 32) {
        const int wo  = tid;
        const int wq  = wo >> 1;
        const int odd = wo & 1;
        // window element order matches pool_windows: e = kh*2 + kw
        float eps[4];
        eps[0] = eps2[odd * 2 + 0][wq];     // top-left
        eps[1] = eps2[odd * 2 + 1][wq];     // top-right
        eps[2] = eps2[4 + odd * 2 + 0][wq]; // bottom-left
        eps[3] = eps2[4 + odd * 2 + 1][wq]; // bottom-right

        const int wbase = rowbase + wo * 2;
        float2 r0 = *(const float2*)(x + wbase);        // center layer (s=0)
        float2 r1 = *(const float2*)(x + wbase + W);
        float x0[4] = { r0.x, r0.y, r1.x, r1.y };
        float lo[4], hi[4];
        #pragma unroll
        for (int e = 0; e < 4; ++e) { lo[e] = x0[e] - eps[e]; hi[e] = x0[e] + eps[e]; }

        int istar = 0;   // first-max tie-break like jnp.argmax
        #pragma unroll
        for (int e = 1; e < 4; ++e) if (lo[e] > lo[istar]) istar = e;

        const float lstar = lo[istar];
        const float umax  = fmaxf(fmaxf(hi[0], hi[1]), fmaxf(hi[2], hi[3]));
        float uoth = -INFINITY;
        #pragma unroll
        for (int e = 0; e < 4; ++e) if (e != istar) uoth = fmaxf(uoth, hi[e]);

        const bool exact = (lstar >= uoth);
        const int  pos   = wbase + (istar & 1) + (istar >> 1) * W;

        // exact: x_max = hi[istar] == umax (since u_other <= lstar <= hi[istar]);
        // box:   x_min = lstar, x_max = umax. x_min = lstar in BOTH branches.
        float center, noise;
        if (exact) {
            center = x0[istar];
            noise  = fabsf(x[(size_t)(S - 1) * L + pos]);
            int i  = atomicAdd(counter, 1);
            exlist[i] = make_int2(c * 1024 + ho * 32 + wo, pos);
        } else {
            center = 0.5f * (lstar + umax);
            noise  = 0.5f * (umax - lstar);
        }

        const int p = c * 1024 + ho * 32 + wo;
        out[p] = center;                       // x_out layer 0
        out[(size_t)(S - 1) * NP + p] = noise; // x_out noise layer
        out[XOUT + p] = lstar;                 // x_min
        out[XOUT + NP + p] = umax;             // x_max (== hi[istar] when exact)

        float2 t0 = *(const float2*)(x_true + wbase);
        float2 t1 = *(const float2*)(x_true + wbase + W);
        out[XOUT + 2 * NP + p] = fmaxf(fmaxf(t0.x, t0.y), fmaxf(t1.x, t1.y));
    }
}

// ---------------------------------------------------------------------------
// Drain the exact list (normally empty): copy the winning element's affine
// form through the 256 eps layers. Fixed grid (graph-capture safe), strided
// over the runtime count.
// ---------------------------------------------------------------------------
__global__ __launch_bounds__(256) void k_gather(const float* __restrict__ x,
                                                const int* __restrict__ counter,
                                                const int2* __restrict__ exlist,
                                                float* __restrict__ out) {
    const int n = counter[0];
    const int s = 1 + threadIdx.x;            // eps layers 1..256 exactly
    for (int i = blockIdx.x; i < n; i += gridDim.x) {
        const int2 e = exlist[i];
        out[(size_t)s * NP + e.x] = x[(size_t)s * L + e.y];
    }
}

extern "C" void kernel_launch(void* const* d_in, const int* in_sizes, int n_in,
                              void* d_out, int out_size, void* d_ws, size_t ws_size,
                              hipStream_t stream) {
    const float* x      = (const float*)d_in[0];
    const float* x_true = (const float*)d_in[1];
    float* out = (float*)d_out;

    int*  counter = (int*)d_ws;
    int2* exlist  = (int2*)((char*)d_ws + 256);

    // Zero all of x_out (eps layers stay zero except exact windows);
    // the x_min/x_max/x_true_out tail is fully written by k_main.
    hipMemsetAsync(out, 0, (size_t)XOUT * sizeof(float), stream);
    hipMemsetAsync(counter, 0, sizeof(int), stream);

    k_main<<<C * HO, 256, 0, stream>>>(x, x_true, out, counter, exlist);
    k_gather<<<64, 256, 0, stream>>>(x, counter, exlist, out);
}

// Round 3
// 386.206 us; speedup vs baseline: 1.0404x; 1.0195x over previous
//
#include <hip/hip_runtime.h>
#include <math.h>

// Problem constants (from setup_inputs): x [S,C,H,W] fp32, k = stride = 2
#define S    258
#define C    64
#define H    64
#define W    64
#define HO   32
#define WO   32
#define NP   (C * HO * WO)      // 65536 windows per layer
#define L    (C * H * W)        // 262144 floats per layer
#define XOUT (S * NP)           // x_out element count

// ---------------------------------------------------------------------------
// Single fused kernel. One block per (c, ho) row-pair = 32 windows.
//   Phase 0: zero-fill this block's slice of the 256 eps layers of x_out
//            (fire-and-forget stores; overlap with the read stream below).
//   Phase 1: 256 threads = 16 layer-groups x 16 float4-columns stream the
//            257 symbol layers (|.| sums), float4 loads (16 B/lane).
//   Phase 2: LDS tree-reduce across the 16 layer-groups.
//   Phase 3: threads 0..31 (one per window) make the zonotope decision and
//            write center / noise / x_min / x_max / x_true_out; `exact`
//            windows (statistically ~never with 257 eps layers) are queued
//            in LDS.
//   Phase 4: cooperative overwrite of eps layers for queued exact windows
//            (256 threads <-> 256 eps layers, one each). Barrier between
//            phase 0 stores and phase 4 stores orders same-address writes.
// ---------------------------------------------------------------------------
__global__ __launch_bounds__(256) void k_fused(const float* __restrict__ x,
                                               const float* __restrict__ x_true,
                                               float* __restrict__ out) {
    __shared__ float red[16][8][16];   // [layer-group][elem][col-pair]
    __shared__ float eps2[8][16];
    __shared__ int   ex_p[32];         // exact window ids (global p)
    __shared__ int   ex_pos[32];       // winning element position in layer
    __shared__ int   ex_n;

    const int b   = blockIdx.x;
    const int c   = b >> 5;
    const int ho  = b & 31;
    const int tid = threadIdx.x;
    const int sg  = tid >> 4;          // layer group 0..15
    const int wp  = tid & 15;          // float4 column (covers windows 2wp,2wp+1)

    if (tid == 0) ex_n = 0;

    const int p0      = b * 32;                      // first window id of block
    const int rowbase = c * (H * W) + ho * 2 * W;    // start of top input row

    // Phase 0: zero the block's slice of eps layers s=1..256 (32 KB).
    #pragma unroll 4
    for (int i = tid; i < 256 * 32; i += 256) {
        const int s = 1 + (i >> 5);
        out[(size_t)s * NP + p0 + (i & 31)] = 0.0f;
    }

    // Phase 1: layers 1..257 split into 16 contiguous ranges
    const int s0 = 1 + ((257 * sg) >> 4);
    const int s1 = 1 + ((257 * (sg + 1)) >> 4);
    const int A  = rowbase + wp * 4;

    float a0=0.f,a1=0.f,a2=0.f,a3=0.f,a4=0.f,a5=0.f,a6=0.f,a7=0.f;
    const float* px = x + (size_t)s0 * L + A;
    for (int s = s0; s < s1; ++s) {
        float4 t = *(const float4*)(px);        // top row: windows 2wp,2wp+1
        float4 u = *(const float4*)(px + W);    // bottom row
        a0 += fabsf(t.x); a1 += fabsf(t.y); a2 += fabsf(t.z); a3 += fabsf(t.w);
        a4 += fabsf(u.x); a5 += fabsf(u.y); a6 += fabsf(u.z); a7 += fabsf(u.w);
        px += L;
    }
    red[sg][0][wp]=a0; red[sg][1][wp]=a1; red[sg][2][wp]=a2; red[sg][3][wp]=a3;
    red[sg][4][wp]=a4; red[sg][5][wp]=a5; red[sg][6][wp]=a6; red[sg][7][wp]=a7;
    __syncthreads();

    // Phase 2: reduce 16 layer-groups
    if (tid < 128) {
        const int e = tid >> 4, w = tid & 15;
        float sum = 0.f;
        #pragma unroll
        for (int j = 0; j < 16; ++j) sum += red[j][e][w];
        eps2[e][w] = sum;
    }
    __syncthreads();

    // Phase 3: per-window decision
    if (tid < 32) {
        const int wo  = tid;
        const int wq  = wo >> 1;
        const int odd = wo & 1;
        // window element order matches pool_windows: e = kh*2 + kw
        float eps[4];
        eps[0] = eps2[odd * 2 + 0][wq];
        eps[1] = eps2[odd * 2 + 1][wq];
        eps[2] = eps2[4 + odd * 2 + 0][wq];
        eps[3] = eps2[4 + odd * 2 + 1][wq];

        const int wbase = rowbase + wo * 2;
        float2 r0 = *(const float2*)(x + wbase);        // center layer (s=0)
        float2 r1 = *(const float2*)(x + wbase + W);
        float x0[4] = { r0.x, r0.y, r1.x, r1.y };
        float lo[4], hi[4];
        #pragma unroll
        for (int e = 0; e < 4; ++e) { lo[e] = x0[e] - eps[e]; hi[e] = x0[e] + eps[e]; }

        int istar = 0;   // first-max tie-break like jnp.argmax
        #pragma unroll
        for (int e = 1; e < 4; ++e) if (lo[e] > lo[istar]) istar = e;

        const float lstar = lo[istar];
        const float umax  = fmaxf(fmaxf(hi[0], hi[1]), fmaxf(hi[2], hi[3]));
        float uoth = -INFINITY;
        #pragma unroll
        for (int e = 0; e < 4; ++e) if (e != istar) uoth = fmaxf(uoth, hi[e]);

        const bool exact = (lstar >= uoth);
        const int  pos   = wbase + (istar & 1) + (istar >> 1) * W;

        // exact: x_max = hi[istar] == umax (u_other <= lstar <= hi[istar]);
        // box:   x_min = lstar, x_max = umax. x_min = lstar in BOTH branches.
        float center, noise;
        if (exact) {
            center = x0[istar];
            noise  = fabsf(x[(size_t)(S - 1) * L + pos]);
            int i  = atomicAdd(&ex_n, 1);
            ex_p[i]   = p0 + wo;
            ex_pos[i] = pos;
        } else {
            center = 0.5f * (lstar + umax);
            noise  = 0.5f * (umax - lstar);
        }

        const int p = p0 + wo;
        out[p] = center;                       // x_out layer 0
        out[(size_t)(S - 1) * NP + p] = noise; // x_out noise layer
        out[XOUT + p] = lstar;                 // x_min
        out[XOUT + NP + p] = umax;             // x_max

        float2 t0 = *(const float2*)(x_true + wbase);
        float2 t1 = *(const float2*)(x_true + wbase + W);
        out[XOUT + 2 * NP + p] = fmaxf(fmaxf(t0.x, t0.y), fmaxf(t1.x, t1.y));
    }
    __syncthreads();   // drains phase-0 zero stores before any overwrite

    // Phase 4: rare exact windows — copy the winning element's affine form
    // through eps layers 1..256 (one layer per thread).
    const int n = ex_n;
    for (int j = 0; j < n; ++j) {
        const int s = 1 + tid;   // 1..256
        out[(size_t)s * NP + ex_p[j]] = x[(size_t)s * L + ex_pos[j]];
    }
}

extern "C" void kernel_launch(void* const* d_in, const int* in_sizes, int n_in,
                              void* d_out, int out_size, void* d_ws, size_t ws_size,
                              hipStream_t stream) {
    const float* x      = (const float*)d_in[0];
    const float* x_true = (const float*)d_in[1];
    float* out = (float*)d_out;
    k_fused<<<C * HO, 256, 0, stream>>>(x, x_true, out);
}

// Round 4
// 384.372 us; speedup vs baseline: 1.0454x; 1.0048x over previous
//
#include <hip/hip_runtime.h>
#include <math.h>

// Problem constants (from setup_inputs): x [S,C,H,W] fp32, k = stride = 2
#define S    258
#define C    64
#define H    64
#define W    64
#define NP   65536              // windows per layer (C*32*32)
#define L    262144             // floats per layer (C*H*W)
#define XOUT (S * NP)           // x_out element count
#define NSC  8                  // s-chunks
#define NQ   4                  // quarters per channel (16 input rows each)

// ---------------------------------------------------------------------------
// Kernel 1: partial |x| sums with fully-contiguous memory access.
// Grid 2048 = (sc, c, q). Per block:
//   - zero a contiguous 32 KB slice of the eps-layer region of x_out
//   - stream 32..33 layers x 4 KB contiguous (1 float4/thread/layer),
//     accumulating |.| into a float4 per thread
//   - write a contiguous 4 KB partial
// All 2048 blocks are co-resident (8/CU); at any instant the grid reads 8
// full 1 MB layers densely -> even HBM channel utilization.
// ---------------------------------------------------------------------------
__global__ __launch_bounds__(256) void k_partial(const float* __restrict__ x,
                                                 float* __restrict__ part,
                                                 float* __restrict__ out) {
    const int b  = blockIdx.x;           // sc*256 + c*4 + q
    const int sc = b >> 8;
    const int c  = (b >> 2) & 63;
    const int q  = b & 3;
    const int t  = threadIdx.x;

    // Fire-and-forget contiguous zero of 8192 floats of eps layers (s=1..256).
    // 2048 blocks x 8192 = 256*NP floats == the whole eps region.
    {
        float4 z = make_float4(0.f, 0.f, 0.f, 0.f);
        float4* zp = (float4*)(out + NP) + (size_t)b * 2048 + t;
        #pragma unroll
        for (int i = 0; i < 8; ++i) zp[i * 256] = z;
    }

    // layers 1..257 split into 8 contiguous ranges (32,32,...,33)
    const int s0 = 1 + ((257 * sc) >> 3);
    const int s1 = 1 + ((257 * (sc + 1)) >> 3);

    const int base = c * (H * W) + q * 1024 + 4 * t;   // quarter-contiguous
    const float* px = x + (size_t)s0 * L + base;
    float4 acc = make_float4(0.f, 0.f, 0.f, 0.f);
    #pragma unroll 4
    for (int s = s0; s < s1; ++s) {
        float4 v = *(const float4*)px;
        acc.x += fabsf(v.x); acc.y += fabsf(v.y);
        acc.z += fabsf(v.z); acc.w += fabsf(v.w);
        px += L;
    }
    // part[sc][c][q][1024], contiguous 4 KB per block
    *(float4*)(part + (size_t)sc * L + c * (H * W) + q * 1024 + 4 * t) = acc;
}

// ---------------------------------------------------------------------------
// Kernel 2: reduce partials + zonotope decision. Grid 256 = (c, q),
// one thread per window (r = t>>5 in 0..7, wo = t&31).
// Writes center / noise / x_min / x_max / x_true_out; rare `exact` windows
// are queued in LDS and their affine forms copied cooperatively
// (256 threads <-> eps layers 1..256).
// ---------------------------------------------------------------------------
__global__ __launch_bounds__(256) void k_decide(const float* __restrict__ x,
                                                const float* __restrict__ x_true,
                                                const float* __restrict__ part,
                                                float* __restrict__ out) {
    __shared__ int ex_n;
    __shared__ int ex_p[256];
    __shared__ int ex_pos[256];

    const int b = blockIdx.x;
    const int c = b >> 2;
    const int q = b & 3;
    const int t = threadIdx.x;
    if (t == 0) ex_n = 0;
    __syncthreads();

    const int r  = t >> 5;                 // window row within quarter
    const int wo = t & 31;                 // window col
    const int qbase   = c * (H * W) + q * 1024;       // layer-local quarter base
    const int loc_top = (2 * r) * W + 2 * wo;         // within quarter
    const int loc_bot = loc_top + W;

    // eps reduce over 8 chunks (part is L2-hot, 8 MB)
    float e0 = 0.f, e1 = 0.f, e2 = 0.f, e3 = 0.f;
    #pragma unroll
    for (int sc = 0; sc < NSC; ++sc) {
        const float* pp = part + (size_t)sc * L + qbase;
        float2 a = *(const float2*)(pp + loc_top);
        float2 d = *(const float2*)(pp + loc_bot);
        e0 += a.x; e1 += a.y; e2 += d.x; e3 += d.y;
    }

    float2 r0 = *(const float2*)(x + qbase + loc_top);   // center layer (s=0)
    float2 r1 = *(const float2*)(x + qbase + loc_bot);
    // window element order matches pool_windows: e = kh*2 + kw
    float x0[4]  = { r0.x, r0.y, r1.x, r1.y };
    float eps[4] = { e0, e1, e2, e3 };
    float lo[4], hi[4];
    #pragma unroll
    for (int e = 0; e < 4; ++e) { lo[e] = x0[e] - eps[e]; hi[e] = x0[e] + eps[e]; }

    int istar = 0;   // first-max tie-break like jnp.argmax
    #pragma unroll
    for (int e = 1; e < 4; ++e) if (lo[e] > lo[istar]) istar = e;

    const float lstar = lo[istar];
    const float umax  = fmaxf(fmaxf(hi[0], hi[1]), fmaxf(hi[2], hi[3]));
    float uoth = -INFINITY;
    #pragma unroll
    for (int e = 0; e < 4; ++e) if (e != istar) uoth = fmaxf(uoth, hi[e]);

    const bool exact = (lstar >= uoth);
    const int  pos   = qbase + loc_top + (istar & 1) + (istar >> 1) * W;

    // exact: x_max = hi[istar] == umax (u_other <= lstar <= hi[istar]);
    // box:   x_min = lstar, x_max = umax. x_min = lstar in BOTH branches.
    float center, noise;
    if (exact) {
        center = x0[istar];
        noise  = fabsf(x[(size_t)(S - 1) * L + pos]);
        int i  = atomicAdd(&ex_n, 1);
        ex_p[i]   = c * 1024 + q * 256 + t;
        ex_pos[i] = pos;
    } else {
        center = 0.5f * (lstar + umax);
        noise  = 0.5f * (umax - lstar);
    }

    const int p = c * 1024 + q * 256 + t;  // = c*1024 + (8q+r)*32 + wo
    out[p] = center;                        // x_out layer 0
    out[(size_t)(S - 1) * NP + p] = noise;  // x_out noise layer
    out[XOUT + p] = lstar;                  // x_min
    out[XOUT + NP + p] = umax;              // x_max

    float2 t0 = *(const float2*)(x_true + qbase + loc_top);
    float2 t1 = *(const float2*)(x_true + qbase + loc_bot);
    out[XOUT + 2 * NP + p] = fmaxf(fmaxf(t0.x, t0.y), fmaxf(t1.x, t1.y));

    __syncthreads();
    // Rare exact windows: copy the winning element's affine form through
    // eps layers 1..256, one layer per thread. Runs after k_partial's zeros
    // (dispatch boundary orders them).
    const int n = ex_n;
    for (int j = 0; j < n; ++j) {
        out[(size_t)(1 + t) * NP + ex_p[j]] = x[(size_t)(1 + t) * L + ex_pos[j]];
    }
}

extern "C" void kernel_launch(void* const* d_in, const int* in_sizes, int n_in,
                              void* d_out, int out_size, void* d_ws, size_t ws_size,
                              hipStream_t stream) {
    const float* x      = (const float*)d_in[0];
    const float* x_true = (const float*)d_in[1];
    float* out  = (float*)d_out;
    float* part = (float*)d_ws;            // NSC * L floats = 8 MB

    k_partial<<<NSC * C * NQ, 256, 0, stream>>>(x, part, out);
    k_decide<<<C * NQ, 256, 0, stream>>>(x, x_true, part, out);
}